// Round 5
// baseline (135.066 us; speedup 1.0000x reference)
//
#include <hip/hip_runtime.h>
#include <hip/hip_bf16.h>
#include <math.h>

// Problem constants (fixed shapes from setup_inputs)
#define NB    8
#define CIN   128
#define CO    32
#define CH    64          // 2*Co channels in qk
#define NN    65536       // H*W
#define CHUNKS 128        // gram chunks per batch (= blocks per batch)
#define SPC   (NN/CHUNKS) // 512 spatial columns per chunk
#define SPW   (SPC/4)     // 128 columns per wave
#define SLABS (SPW/16)    // 8 K=16 MFMA slabs per wave

typedef __attribute__((ext_vector_type(8))) short bf16x8;
typedef __attribute__((ext_vector_type(16))) float f32x16;

__device__ __forceinline__ short f2bf(float f) {
    union { __hip_bfloat16 h; short s; } u;
    u.h = __float2bfloat16(f);
    return u.s;
}
__device__ __forceinline__ float bf2f(short s) {
    union { __hip_bfloat16 h; short s; } u;
    u.s = s;
    return __bfloat162float(u.h);
}

// ---------------------------------------------------------------------------
// Kernel A (MFMA, occupancy v3 — unchanged from R4): block = one chunk
// (512 cols), 4 waves split it 128 cols each; 32x32x16 bf16 MFMA with hi/lo
// split (err ~2^-18); fragments straight from global. Cross-wave LDS reduce.
// ---------------------------------------------------------------------------
__global__ __launch_bounds__(256) void gram_kernel(const float* __restrict__ qk,
                                                   float* __restrict__ part,
                                                   float* __restrict__ partsq) {
    __shared__ float red[4 * 1024];
    __shared__ float red2[4 * 64];

    const int b = blockIdx.y;
    const int chunk = blockIdx.x;
    const int w = threadIdx.x >> 6;
    const int l = threadIdx.x & 63;
    const int c = l & 31;       // channel (row for A / col for B)
    const int half = l >> 5;    // k-half selector

    const size_t colbase = (size_t)chunk * SPC + (size_t)w * SPW + half * 8;
    const float* qrow = qk + (size_t)b * CH * NN + (size_t)(CO + c) * NN + colbase;
    const float* krow = qk + (size_t)b * CH * NN + (size_t)c * NN + colbase;

    f32x16 acc = {};
    float sqq = 0.f, sqk = 0.f;

#pragma unroll 2
    for (int s = 0; s < SLABS; ++s) {
        float4 q0 = *(const float4*)(qrow + s * 16);
        float4 q1 = *(const float4*)(qrow + s * 16 + 4);
        float4 k0 = *(const float4*)(krow + s * 16);
        float4 k1 = *(const float4*)(krow + s * 16 + 4);

        float qf[8] = {q0.x, q0.y, q0.z, q0.w, q1.x, q1.y, q1.z, q1.w};
        float kf[8] = {k0.x, k0.y, k0.z, k0.w, k1.x, k1.y, k1.z, k1.w};

        bf16x8 ah, al, bh, bl;
#pragma unroll
        for (int j = 0; j < 8; ++j) {
            short hq = f2bf(qf[j]);
            ah[j] = hq;
            al[j] = f2bf(qf[j] - bf2f(hq));
            short hk = f2bf(kf[j]);
            bh[j] = hk;
            bl[j] = f2bf(kf[j] - bf2f(hk));
            sqq = fmaf(qf[j], qf[j], sqq);   // square-sums in full f32
            sqk = fmaf(kf[j], kf[j], sqk);
        }
        acc = __builtin_amdgcn_mfma_f32_32x32x16_bf16(ah, bh, acc, 0, 0, 0);
        acc = __builtin_amdgcn_mfma_f32_32x32x16_bf16(ah, bl, acc, 0, 0, 0);
        acc = __builtin_amdgcn_mfma_f32_32x32x16_bf16(al, bh, acc, 0, 0, 0);
    }

    // square-sums: combine k-halves (same channel set on both halves)
    sqq += __shfl_xor(sqq, 32);
    sqk += __shfl_xor(sqk, 32);
    if (half == 0) {
        red2[w * 64 + c] = sqk;
        red2[w * 64 + 32 + c] = sqq;
    }

    // C/D layout (m74/m101): col = lane&31, row = (r&3) + 8*(r>>2) + 4*(lane>>5)
#pragma unroll
    for (int r = 0; r < 16; ++r) {
        int row = (r & 3) + 8 * (r >> 2) + 4 * half;   // q index
        red[w * 1024 + row * 32 + c] = acc[r];
    }
    __syncthreads();

    float* pp = part + ((size_t)b * CHUNKS + chunk) * 1024;
#pragma unroll
    for (int k = 0; k < 4; ++k) {
        int idx = threadIdx.x + k * 256;
        pp[idx] = red[idx] + red[1024 + idx] + red[2048 + idx] + red[3072 + idx];
    }
    if (threadIdx.x < 64) {
        partsq[((size_t)b * CHUNKS + chunk) * 64 + threadIdx.x] =
            red2[threadIdx.x] + red2[64 + threadIdx.x] +
            red2[128 + threadIdx.x] + red2[192 + threadIdx.x];
    }
}

// ---------------------------------------------------------------------------
// Kernel B (merged finalize — unchanged from R4)
// ---------------------------------------------------------------------------
__global__ __launch_bounds__(256) void finalize_kernel(const float* __restrict__ part,
                                                       const float* __restrict__ partsq,
                                                       const float* __restrict__ w_v,
                                                       const float* __restrict__ b_v,
                                                       const float* __restrict__ temp,
                                                       float* __restrict__ Weff,
                                                       float* __restrict__ beff) {
    __shared__ float sS[1024];
    __shared__ float snorm[64];
    __shared__ float sA[1024];
    const int t = threadIdx.x;
    const int b = blockIdx.x;

    for (int v = t; v < 1024; v += 256) {
        const float* p = part + (size_t)b * CHUNKS * 1024 + v;
        float s = 0.f;
#pragma unroll 16
        for (int ch = 0; ch < CHUNKS; ++ch)
            s += p[(size_t)ch * 1024];
        sS[v] = s;
    }
    if (t < 64) {
        const float* p = partsq + (size_t)b * CHUNKS * 64 + t;
        float s = 0.f;
#pragma unroll 16
        for (int ch = 0; ch < CHUNKS; ++ch)
            s += p[(size_t)ch * 64];
        snorm[t] = fmaxf(sqrtf(s), 1e-12f);
    }
    __syncthreads();

    if (t < 32) {
        const float T = temp[0];
        const float qn = snorm[32 + t];
        float m = -1e30f;
        for (int d = 0; d < 32; ++d)
            m = fmaxf(m, sS[t * 32 + d] / (qn * snorm[d]) * T);
        float sum = 0.f;
        for (int d = 0; d < 32; ++d)
            sum += expf(sS[t * 32 + d] / (qn * snorm[d]) * T - m);
        const float inv = 1.f / sum;
        for (int d = 0; d < 32; ++d)
            sA[t * 32 + d] = expf(sS[t * 32 + d] / (qn * snorm[d]) * T - m) * inv;
    }
    __syncthreads();

    for (int idx = t; idx < CO * CIN; idx += 256) {
        int cc = idx >> 7;
        int ci = idx & 127;
        float s = 0.f;
#pragma unroll
        for (int d = 0; d < 32; ++d) s += sA[cc * 32 + d] * w_v[d * CIN + ci];
        Weff[(size_t)b * CO * CIN + idx] = s;
    }
    if (t < 32) {
        float s = 0.f;
#pragma unroll
        for (int d = 0; d < 32; ++d) s += sA[t * 32 + d] * b_v[d];
        beff[b * CO + t] = s;
    }
}

// ---------------------------------------------------------------------------
// Kernel C: out v1 (EXACT R1/R3 code — scalar uniform W loads, float2 x).
// ---------------------------------------------------------------------------
__global__ __launch_bounds__(256) void out_kernel(const float* __restrict__ x,
                                                  const float* __restrict__ Weff,
                                                  const float* __restrict__ beff,
                                                  float* __restrict__ out) {
    const int b = blockIdx.y;
    const int n0 = blockIdx.x * 512 + threadIdx.x * 2;
    const float* xb = x + (size_t)b * CIN * NN + n0;
    const float* Wb = Weff + (size_t)b * CO * CIN;
    const float* bb = beff + b * CO;

    float a0[CO], a1[CO];
#pragma unroll
    for (int o = 0; o < CO; ++o) { a0[o] = bb[o]; a1[o] = bb[o]; }

#pragma unroll 4
    for (int ci = 0; ci < CIN; ++ci) {
        float2 xv = *(const float2*)(xb + (size_t)ci * NN);
#pragma unroll
        for (int o = 0; o < CO; ++o) {
            float wv = Wb[o * CIN + ci];
            a0[o] = fmaf(wv, xv.x, a0[o]);
            a1[o] = fmaf(wv, xv.y, a1[o]);
        }
    }

    float* ob = out + (size_t)b * CO * NN + n0;
#pragma unroll
    for (int o = 0; o < CO; ++o) {
        float2 r;
        r.x = a0[o];
        r.y = a1[o];
        *(float2*)(ob + (size_t)o * NN) = r;
    }
}

// ---------------------------------------------------------------------------
extern "C" void kernel_launch(void* const* d_in, const int* in_sizes, int n_in,
                              void* d_out, int out_size, void* d_ws, size_t ws_size,
                              hipStream_t stream) {
    const float* x    = (const float*)d_in[0];
    const float* qk   = (const float*)d_in[1];
    const float* w_v  = (const float*)d_in[2];
    const float* b_v  = (const float*)d_in[3];
    const float* temp = (const float*)d_in[4];
    float* out = (float*)d_out;

    float* part   = (float*)d_ws;                       // NB*CHUNKS*1024 floats (4 MB)
    float* partsq = part + (size_t)NB * CHUNKS * 1024;  // NB*CHUNKS*64 floats (256 KB)
    float* Weff   = partsq + (size_t)NB * CHUNKS * 64;  // NB*CO*CIN floats
    float* beff   = Weff + (size_t)NB * CO * CIN;       // NB*CO floats

    gram_kernel<<<dim3(CHUNKS, NB), 256, 0, stream>>>(qk, part, partsq);
    finalize_kernel<<<dim3(NB), 256, 0, stream>>>(part, partsq, w_v, b_v, temp, Weff, beff);
    out_kernel<<<dim3(NN / 512, NB), 256, 0, stream>>>(x, Weff, beff, out);
}

// Round 6
// 125.996 us; speedup vs baseline: 1.0720x; 1.0720x over previous
//
#include <hip/hip_runtime.h>
#include <hip/hip_bf16.h>
#include <math.h>

// Problem constants (fixed shapes from setup_inputs)
#define NB    8
#define CIN   128
#define CO    32
#define CH    64          // 2*Co channels in qk
#define NN    65536       // H*W
#define CHUNKS 128        // gram chunks per batch (= blocks per batch)
#define SPC   (NN/CHUNKS) // 512 spatial columns per chunk
#define WPB   8           // waves per gram block (512 threads)
#define SPW   (SPC/WPB)   // 64 columns per wave
#define SLABS (SPW/16)    // 4 K=16 MFMA slabs per wave

typedef __attribute__((ext_vector_type(8))) short bf16x8;
typedef __attribute__((ext_vector_type(16))) float f32x16;

__device__ __forceinline__ short f2bf(float f) {
    union { __hip_bfloat16 h; short s; } u;
    u.h = __float2bfloat16(f);
    return u.s;
}
__device__ __forceinline__ float bf2f(short s) {
    union { __hip_bfloat16 h; short s; } u;
    u.s = s;
    return __bfloat162float(u.h);
}

// ---------------------------------------------------------------------------
// Kernel A (MFMA, v4 — 32 waves/CU): block = one chunk (512 cols), 8 waves x
// 64 cols; 4 fully-unrolled slabs -> 16 independent b128 loads in flight per
// wave. 32x32x16 bf16 MFMA hi/lo split (err ~2^-18), fragments straight from
// global (lane&31 = channel, lane>>5 = k-half). Cross-wave LDS reduce.
//   part[b][chunk][q*32+k], partsq[b][chunk][c] (0..31=k, 32..63=q)
// ---------------------------------------------------------------------------
__global__ __launch_bounds__(512) void gram_kernel(const float* __restrict__ qk,
                                                   float* __restrict__ part,
                                                   float* __restrict__ partsq) {
    __shared__ float red[WPB * 1024];   // 32 KB
    __shared__ float red2[WPB * 64];    // 2 KB

    const int b = blockIdx.y;
    const int chunk = blockIdx.x;
    const int t = threadIdx.x;
    const int w = t >> 6;
    const int l = t & 63;
    const int c = l & 31;       // channel (row for A / col for B)
    const int half = l >> 5;    // k-half selector

    const size_t colbase = (size_t)chunk * SPC + (size_t)w * SPW + half * 8;
    const float* qrow = qk + (size_t)b * CH * NN + (size_t)(CO + c) * NN + colbase;
    const float* krow = qk + (size_t)b * CH * NN + (size_t)c * NN + colbase;

    // ---- issue all 16 loads up front (independent, fill the VMEM queue)
    float4 qA[SLABS][2], kA[SLABS][2];
#pragma unroll
    for (int s = 0; s < SLABS; ++s) {
        qA[s][0] = *(const float4*)(qrow + s * 16);
        qA[s][1] = *(const float4*)(qrow + s * 16 + 4);
        kA[s][0] = *(const float4*)(krow + s * 16);
        kA[s][1] = *(const float4*)(krow + s * 16 + 4);
    }

    f32x16 acc = {};
    float sqq = 0.f, sqk = 0.f;

#pragma unroll
    for (int s = 0; s < SLABS; ++s) {
        float qf[8] = {qA[s][0].x, qA[s][0].y, qA[s][0].z, qA[s][0].w,
                       qA[s][1].x, qA[s][1].y, qA[s][1].z, qA[s][1].w};
        float kf[8] = {kA[s][0].x, kA[s][0].y, kA[s][0].z, kA[s][0].w,
                       kA[s][1].x, kA[s][1].y, kA[s][1].z, kA[s][1].w};

        bf16x8 ah, al, bh, bl;
#pragma unroll
        for (int j = 0; j < 8; ++j) {
            short hq = f2bf(qf[j]);
            ah[j] = hq;
            al[j] = f2bf(qf[j] - bf2f(hq));
            short hk = f2bf(kf[j]);
            bh[j] = hk;
            bl[j] = f2bf(kf[j] - bf2f(hk));
            sqq = fmaf(qf[j], qf[j], sqq);   // square-sums in full f32
            sqk = fmaf(kf[j], kf[j], sqk);
        }
        acc = __builtin_amdgcn_mfma_f32_32x32x16_bf16(ah, bh, acc, 0, 0, 0);
        acc = __builtin_amdgcn_mfma_f32_32x32x16_bf16(ah, bl, acc, 0, 0, 0);
        acc = __builtin_amdgcn_mfma_f32_32x32x16_bf16(al, bh, acc, 0, 0, 0);
    }

    // square-sums: combine k-halves (same channel set on both halves)
    sqq += __shfl_xor(sqq, 32);
    sqk += __shfl_xor(sqk, 32);
    if (half == 0) {
        red2[w * 64 + c] = sqk;
        red2[w * 64 + 32 + c] = sqq;
    }

    // C/D layout (m74/m101): col = lane&31, row = (r&3) + 8*(r>>2) + 4*(lane>>5)
#pragma unroll
    for (int r = 0; r < 16; ++r) {
        int row = (r & 3) + 8 * (r >> 2) + 4 * half;   // q index
        red[w * 1024 + row * 32 + c] = acc[r];
    }
    __syncthreads();

    // ---- cross-wave reduce (8 ways) + write partials
    float* pp = part + ((size_t)b * CHUNKS + chunk) * 1024;
#pragma unroll
    for (int k = 0; k < 2; ++k) {
        int idx = t + k * 512;
        float s = 0.f;
#pragma unroll
        for (int ww = 0; ww < WPB; ++ww) s += red[ww * 1024 + idx];
        pp[idx] = s;
    }
    if (t < 64) {
        float s = 0.f;
#pragma unroll
        for (int ww = 0; ww < WPB; ++ww) s += red2[ww * 64 + t];
        partsq[((size_t)b * CHUNKS + chunk) * 64 + t] = s;
    }
}

// ---------------------------------------------------------------------------
// Kernel B1: reduce partials over chunks -> Sred[b][0..1023]=S, [1024..1087]=sumsq
// (R1 version — 136 blocks for parallelism)
// ---------------------------------------------------------------------------
__global__ __launch_bounds__(128) void reduce_kernel(const float* __restrict__ part,
                                                     const float* __restrict__ partsq,
                                                     float* __restrict__ Sred) {
    const int b = blockIdx.y;
    const int v = blockIdx.x * 64 + (threadIdx.x >> 1);
    const int h = threadIdx.x & 1;
    float s = 0.f;
    if (v < 1024) {
        const float* p = part + (size_t)b * CHUNKS * 1024 + v;
        for (int ch = h * (CHUNKS / 2); ch < (h + 1) * (CHUNKS / 2); ++ch)
            s += p[(size_t)ch * 1024];
    } else {
        const float* p = partsq + (size_t)b * CHUNKS * 64 + (v - 1024);
        for (int ch = h * (CHUNKS / 2); ch < (h + 1) * (CHUNKS / 2); ++ch)
            s += p[(size_t)ch * 64];
    }
    s += __shfl_xor(s, 1);
    if (h == 0) Sred[b * 1088 + v] = s;
}

// ---------------------------------------------------------------------------
// Kernel B2: per batch: normalize, softmax, W_eff = attn @ w_v, b_eff = attn @ b_v
// (R1 version)
// ---------------------------------------------------------------------------
__global__ __launch_bounds__(256) void attn_kernel(const float* __restrict__ Sred,
                                                   const float* __restrict__ w_v,
                                                   const float* __restrict__ b_v,
                                                   const float* __restrict__ temp,
                                                   float* __restrict__ Weff,
                                                   float* __restrict__ beff) {
    __shared__ float sS[1024];
    __shared__ float snorm[64];
    __shared__ float sA[1024];
    const int t = threadIdx.x;
    const int b = blockIdx.x;

    for (int i = t; i < 1024; i += 256) sS[i] = Sred[b * 1088 + i];
    if (t < 64) snorm[t] = fmaxf(sqrtf(Sred[b * 1088 + 1024 + t]), 1e-12f);
    __syncthreads();

    if (t < 32) {
        const float T = temp[0];
        const float qn = snorm[32 + t];
        float m = -1e30f;
        for (int d = 0; d < 32; ++d)
            m = fmaxf(m, sS[t * 32 + d] / (qn * snorm[d]) * T);
        float sum = 0.f;
        for (int d = 0; d < 32; ++d)
            sum += expf(sS[t * 32 + d] / (qn * snorm[d]) * T - m);
        const float inv = 1.f / sum;
        for (int d = 0; d < 32; ++d)
            sA[t * 32 + d] = expf(sS[t * 32 + d] / (qn * snorm[d]) * T - m) * inv;
    }
    __syncthreads();

    for (int idx = t; idx < CO * CIN; idx += 256) {
        int cc = idx >> 7;
        int ci = idx & 127;
        float s = 0.f;
#pragma unroll
        for (int d = 0; d < 32; ++d) s += sA[cc * 32 + d] * w_v[d * CIN + ci];
        Weff[(size_t)b * CO * CIN + idx] = s;
    }
    if (t < 32) {
        float s = 0.f;
#pragma unroll
        for (int d = 0; d < 32; ++d) s += sA[t * 32 + d] * b_v[d];
        beff[b * CO + t] = s;
    }
}

// ---------------------------------------------------------------------------
// Kernel C: out v1 (EXACT R1/R3 code — scalar uniform W loads, float2 x).
// ---------------------------------------------------------------------------
__global__ __launch_bounds__(256) void out_kernel(const float* __restrict__ x,
                                                  const float* __restrict__ Weff,
                                                  const float* __restrict__ beff,
                                                  float* __restrict__ out) {
    const int b = blockIdx.y;
    const int n0 = blockIdx.x * 512 + threadIdx.x * 2;
    const float* xb = x + (size_t)b * CIN * NN + n0;
    const float* Wb = Weff + (size_t)b * CO * CIN;
    const float* bb = beff + b * CO;

    float a0[CO], a1[CO];
#pragma unroll
    for (int o = 0; o < CO; ++o) { a0[o] = bb[o]; a1[o] = bb[o]; }

#pragma unroll 4
    for (int ci = 0; ci < CIN; ++ci) {
        float2 xv = *(const float2*)(xb + (size_t)ci * NN);
#pragma unroll
        for (int o = 0; o < CO; ++o) {
            float wv = Wb[o * CIN + ci];
            a0[o] = fmaf(wv, xv.x, a0[o]);
            a1[o] = fmaf(wv, xv.y, a1[o]);
        }
    }

    float* ob = out + (size_t)b * CO * NN + n0;
#pragma unroll
    for (int o = 0; o < CO; ++o) {
        float2 r;
        r.x = a0[o];
        r.y = a1[o];
        *(float2*)(ob + (size_t)o * NN) = r;
    }
}

// ---------------------------------------------------------------------------
extern "C" void kernel_launch(void* const* d_in, const int* in_sizes, int n_in,
                              void* d_out, int out_size, void* d_ws, size_t ws_size,
                              hipStream_t stream) {
    const float* x    = (const float*)d_in[0];
    const float* qk   = (const float*)d_in[1];
    const float* w_v  = (const float*)d_in[2];
    const float* b_v  = (const float*)d_in[3];
    const float* temp = (const float*)d_in[4];
    float* out = (float*)d_out;

    float* part   = (float*)d_ws;                       // NB*CHUNKS*1024 floats (4 MB)
    float* partsq = part + (size_t)NB * CHUNKS * 1024;  // NB*CHUNKS*64 floats (256 KB)
    float* Sred   = partsq + (size_t)NB * CHUNKS * 64;  // NB*1088 floats
    float* Weff   = Sred + (size_t)NB * 1088;           // NB*CO*CIN floats
    float* beff   = Weff + (size_t)NB * CO * CIN;       // NB*CO floats

    gram_kernel<<<dim3(CHUNKS, NB), 512, 0, stream>>>(qk, part, partsq);
    reduce_kernel<<<dim3(17, NB), 128, 0, stream>>>(part, partsq, Sred);
    attn_kernel<<<dim3(NB), 256, 0, stream>>>(Sred, w_v, b_v, temp, Weff, beff);
    out_kernel<<<dim3(NN / 512, NB), 256, 0, stream>>>(x, Weff, beff, out);
}